// Round 1
// 418.879 us; speedup vs baseline: 1.1501x; 1.1501x over previous
//
#include <hip/hip_runtime.h>
#include <math.h>

// Problem constants
#define BB 16
#define CC 128
#define NN 16384          // 128*128 spatial tokens
#define NHEADS 8
#define HD 16             // head dim
#define SCALE 0.08838834764831843f   // 1/sqrt(128)

typedef __attribute__((ext_vector_type(8))) short short8;
typedef __attribute__((ext_vector_type(4))) unsigned short ushort4v;
typedef __attribute__((ext_vector_type(16))) float f32x16;

// ---------------------------------------------------------------------------
// k1: per-batch partial Gram via split-bf16 MFMA.
// grid (CH, 16 b), 256 threads (4 waves). Block owns NCB = NN/CH tokens.
// x = hi + lo (bf16 RNE hi, bf16 trunc residual); G += hi*hi^T + hi*lo^T +
// lo*hi^T + lo*lo^T with v_mfma_f32_32x32x16_bf16 (fp32 accumulate).
// Wave w handles the 16-token K-slice w of each 64-token stage; each wave
// computes the 10 upper-triangular 32x32 tiles of the 128x128 Gram.
// LDS [ch][64 tok] bf16, XOR-swizzled (byte ^= (ch&7)<<4) so the
// column-strided ds_read_b128 fragment loads are bank-conflict-free.
// A-frag and B-frag layouts coincide for a Gram -> one read serves both.
// ---------------------------------------------------------------------------
__global__ __launch_bounds__(256) void k1_gram(const float* __restrict__ x,
                                               float* __restrict__ pG,
                                               float* __restrict__ pS,
                                               int CH) {
    const int chunk = blockIdx.x;
    const int b = blockIdx.y;
    const int tid = threadIdx.x;
    const int w = tid >> 6;          // wave 0..3
    const int l = tid & 63;
    const int ch0 = tid >> 4;        // staging: channel base 0..15
    const int t4 = tid & 15;         // staging: float4 index within 64-token stage
    const int NCB = NN / CH;
    const int NSTAGE = NCB >> 6;

    __shared__ unsigned short lds[2][2][128 * 64];   // [buf][hi/lo][ch*64+tok], 64 KiB

    const float* xg = x + (size_t)b * CC * NN + (size_t)chunk * NCB;

    f32x16 acc[10];
#pragma unroll
    for (int t = 0; t < 10; ++t)
#pragma unroll
        for (int r = 0; r < 16; ++r) acc[t][r] = 0.0f;

    float csum[8];
#pragma unroll
    for (int k = 0; k < 8; ++k) csum[k] = 0.0f;

    float4 ld[8];

    auto LOAD = [&](int s) {
#pragma unroll
        for (int k = 0; k < 8; ++k)
            ld[k] = *(const float4*)(xg + (size_t)(ch0 + 16 * k) * NN + s * 64 + t4 * 4);
    };

// RNE bf16 hi + truncated bf16 residual lo
#define CVT(comp, hh, ll)                                                    \
    {                                                                        \
        unsigned int u = __float_as_uint(comp);                              \
        unsigned int r = (u + 0x7fffu + ((u >> 16) & 1u)) >> 16;             \
        float lf = (comp) - __uint_as_float(r << 16);                        \
        hh = (unsigned short)r;                                              \
        ll = (unsigned short)(__float_as_uint(lf) >> 16);                    \
    }

    auto CVW = [&](int buf) {
#pragma unroll
        for (int k = 0; k < 8; ++k) {
            float4 v = ld[k];
            csum[k] += v.x + v.y + v.z + v.w;
            const int ch = ch0 + 16 * k;
            const int idx = ((ch << 6) + (t4 << 2)) ^ ((ch & 7) << 3);
            unsigned short h0, h1, h2, h3, l0, l1, l2, l3;
            CVT(v.x, h0, l0)
            CVT(v.y, h1, l1)
            CVT(v.z, h2, l2)
            CVT(v.w, h3, l3)
            ushort4v hv = {h0, h1, h2, h3};
            ushort4v lv = {l0, l1, l2, l3};
            *(ushort4v*)&lds[buf][0][idx] = hv;
            *(ushort4v*)&lds[buf][1][idx] = lv;
        }
    };

    const int lr = l & 31, lh = l >> 5;

    LOAD(0);
    CVW(0);
    __syncthreads();

    for (int s = 0; s < NSTAGE; ++s) {
        const int bsel = s & 1;
        if (s + 1 < NSTAGE) LOAD(s + 1);     // async prefetch under compute

        short8 fh[4], fl[4];
        const int tb = w * 16 + lh * 8;      // token offset of this wave's K-slice
#pragma unroll
        for (int cb = 0; cb < 4; ++cb) {
            const int ch = cb * 32 + lr;
            const int idx = ((ch << 6) + tb) ^ ((ch & 7) << 3);
            fh[cb] = *(const short8*)&lds[bsel][0][idx];
            fl[cb] = *(const short8*)&lds[bsel][1][idx];
        }

#define TILE(t, bi, bj)                                                                      \
        acc[t] = __builtin_amdgcn_mfma_f32_32x32x16_bf16(fh[bi], fh[bj], acc[t], 0, 0, 0);   \
        acc[t] = __builtin_amdgcn_mfma_f32_32x32x16_bf16(fh[bi], fl[bj], acc[t], 0, 0, 0);   \
        acc[t] = __builtin_amdgcn_mfma_f32_32x32x16_bf16(fl[bi], fh[bj], acc[t], 0, 0, 0);   \
        acc[t] = __builtin_amdgcn_mfma_f32_32x32x16_bf16(fl[bi], fl[bj], acc[t], 0, 0, 0);
        TILE(0, 0, 0) TILE(1, 0, 1) TILE(2, 0, 2) TILE(3, 0, 3) TILE(4, 1, 1)
        TILE(5, 1, 2) TILE(6, 1, 3) TILE(7, 2, 2) TILE(8, 2, 3) TILE(9, 3, 3)
#undef TILE

        if (s + 1 < NSTAGE) CVW((s + 1) & 1);
        __syncthreads();
    }

    // ---- channel sums -> pS (reuse LDS as float scratch) ----
    float* scr = (float*)&lds[0][0][0];
#pragma unroll
    for (int k = 0; k < 8; ++k) scr[(ch0 + 16 * k) * 16 + t4] = csum[k];
    __syncthreads();
    if (tid < 128) {
        float s2 = 0.0f;
#pragma unroll
        for (int i = 0; i < 16; ++i) s2 += scr[tid * 16 + i];
        pS[(size_t)(b * CH + chunk) * 128 + tid] = s2;
    }
    __syncthreads();

    // ---- cross-wave reduce of the 10 tiles, store partial Gram ----
    float* outp = pG + (size_t)(b * CH + chunk) * 10240;
#pragma unroll
    for (int half = 0; half < 2; ++half) {
        if (w > 0) {
#pragma unroll
            for (int tt = 0; tt < 5; ++tt)
#pragma unroll
                for (int r = 0; r < 16; ++r)
                    scr[((w - 1) * 5 + tt) * 1024 + r * 64 + l] = acc[half * 5 + tt][r];
        }
        __syncthreads();
        if (w == 0) {
#pragma unroll
            for (int tt = 0; tt < 5; ++tt)
#pragma unroll
                for (int r = 0; r < 16; ++r)
                    outp[(half * 5 + tt) * 1024 + r * 64 + l] =
                        acc[half * 5 + tt][r]
                        + scr[(0 * 5 + tt) * 1024 + r * 64 + l]
                        + scr[(1 * 5 + tt) * 1024 + r * 64 + l]
                        + scr[(2 * 5 + tt) * 1024 + r * 64 + l];
        }
        __syncthreads();
    }
}

// ---------------------------------------------------------------------------
// k1r: reduce partial Grams -> G (with symmetric mirror), pS -> sB.
// grid (41, 16): sg<40 handle the 10*1024 tile elements, sg==40 does sB.
// MFMA C/D layout: col = lane&31, row = (reg&3) + 8*(reg>>2) + 4*(lane>>5).
// ---------------------------------------------------------------------------
__global__ __launch_bounds__(256) void k1_reduce(const float* __restrict__ pG,
                                                 const float* __restrict__ pS,
                                                 float* __restrict__ G,
                                                 float* __restrict__ sB,
                                                 int CH) {
    const int sg = blockIdx.x;
    const int b = blockIdx.y;
    const int tid = threadIdx.x;

    if (sg < 40) {
        const int e = sg * 256 + tid;       // 0..10239
        const int t = e >> 10;              // tile id (uniform per block)
        const int rl = e & 1023;
        float sum = 0.0f;
        const float* p = pG + (size_t)b * CH * 10240 + e;
        for (int ch = 0; ch < CH; ++ch) sum += p[(size_t)ch * 10240];

        int bi, bj;
        if (t < 4)      { bi = 0; bj = t; }
        else if (t < 7) { bi = 1; bj = t - 3; }
        else if (t < 9) { bi = 2; bj = t - 5; }
        else            { bi = 3; bj = 3; }

        const int reg = rl >> 6, lane = rl & 63;
        const int col = bj * 32 + (lane & 31);
        const int row = bi * 32 + (reg & 3) + 8 * (reg >> 2) + 4 * (lane >> 5);
        G[((size_t)b << 14) + row * CC + col] = sum;
        if (bi != bj) G[((size_t)b << 14) + col * CC + row] = sum;
    } else {
        if (tid < 128) {
            float s2 = 0.0f;
            for (int ch = 0; ch < CH; ++ch) s2 += pS[(size_t)(b * CH + ch) * 128 + tid];
            sB[b * CC + tid] = s2;
        }
    }
}

// ---------------------------------------------------------------------------
// k2a: per (b,h) scores + softmax. grid (8 h, 16 b), 256 threads.
// scores = (Wq G Wk^T + (Wq s) bk^T + bq (Wk s)^T + N bq bk^T) * SCALE
// ---------------------------------------------------------------------------
__global__ __launch_bounds__(256) void k2a_attn(const float* __restrict__ G,
                                                const float* __restrict__ sB,
                                                const float* __restrict__ w_qkv,
                                                const float* __restrict__ b_qkv,
                                                float* __restrict__ attn,
                                                float* __restrict__ cpre) {
    const int h = blockIdx.x;
    const int b = blockIdx.y;
    const int tid = threadIdx.x;

    __shared__ float wq_s[HD][132], wk_s[HD][132], Tq[HD][132];
    __shared__ float qs[HD], ks[HD], bqv[HD], bkv[HD], bvv[HD];
    __shared__ float sc[HD][HD + 1];

    for (int idx = tid; idx < HD * CC; idx += 256) {
        int r = idx >> 7, c = idx & 127;
        wq_s[r][c] = w_qkv[(h * HD + r) * CC + c];
        wk_s[r][c] = w_qkv[(CC + h * HD + r) * CC + c];
    }
    if (tid < HD) {
        bqv[tid] = b_qkv[h * HD + tid];
        bkv[tid] = b_qkv[CC + h * HD + tid];
        bvv[tid] = b_qkv[2 * CC + h * HD + tid];
    }
    __syncthreads();

    if (tid < 32) {
        int i = tid & 15;
        bool isK = tid >= 16;
        float sum = 0.0f;
        for (int c = 0; c < CC; ++c)
            sum += (isK ? wk_s[i][c] : wq_s[i][c]) * sB[b * CC + c];
        if (isK) ks[i] = sum; else qs[i] = sum;
    }

    {
        const int c2 = tid & 127;
        const int dh = tid >> 7;
        float t[8];
#pragma unroll
        for (int j = 0; j < 8; ++j) t[j] = 0.0f;
        const float* Gb = G + ((size_t)b << 14);
        for (int c1 = 0; c1 < CC; ++c1) {
            float g = Gb[c1 * CC + c2];
#pragma unroll
            for (int j = 0; j < 8; ++j) t[j] += wq_s[dh * 8 + j][c1] * g;
        }
        __syncthreads();
#pragma unroll
        for (int j = 0; j < 8; ++j) Tq[dh * 8 + j][c2] = t[j];
    }
    __syncthreads();

    {
        const int dd = tid >> 4, e = tid & 15;
        float sum = 0.0f;
        for (int c2 = 0; c2 < CC; ++c2) sum += Tq[dd][c2] * wk_s[e][c2];
        sum += qs[dd] * bkv[e] + bqv[dd] * ks[e] + (float)NN * bqv[dd] * bkv[e];
        sc[dd][e] = sum * SCALE;
    }
    __syncthreads();

    if (tid < HD) {
        const int dd = tid;
        float mx = -1e30f;
#pragma unroll
        for (int e = 0; e < HD; ++e) mx = fmaxf(mx, sc[dd][e]);
        float ex[HD];
        float den = 0.0f;
#pragma unroll
        for (int e = 0; e < HD; ++e) { ex[e] = __expf(sc[dd][e] - mx); den += ex[e]; }
        float inv = 1.0f / den;
        float cp = 0.0f;
#pragma unroll
        for (int e = 0; e < HD; ++e) {
            float a = ex[e] * inv;
            attn[((size_t)b * NHEADS + h) * HD * HD + dd * HD + e] = a;
            cp += a * bvv[e];
        }
        cpre[b * CC + h * HD + dd] = cp;
    }
}

// ---------------------------------------------------------------------------
// k2b: Mt[b][c][o] = (W_out * blockdiag(attn) * W_v)^T, cvec = W_out cpre + b_out
// grid (4 ogroups, 16 b), 256 threads.
// ---------------------------------------------------------------------------
__global__ __launch_bounds__(256) void k2b_M(const float* __restrict__ attn,
                                             const float* __restrict__ cpre,
                                             const float* __restrict__ w_qkv,
                                             const float* __restrict__ w_out,
                                             const float* __restrict__ b_out,
                                             float* __restrict__ Mt,
                                             float* __restrict__ cvec) {
    const int og = blockIdx.x;
    const int b = blockIdx.y;
    const int tid = threadIdx.x;

    __shared__ float Ph[HD][132];
    __shared__ float wo_s[32][129];
    __shared__ float attn_s[CC][HD];
    __shared__ float cpre_s[CC];

    for (int idx = tid; idx < CC * HD; idx += 256)
        attn_s[idx >> 4][idx & 15] = attn[(size_t)b * CC * HD + idx];
    for (int idx = tid; idx < 32 * CC; idx += 256)
        wo_s[idx >> 7][idx & 127] = w_out[(og * 32 + (idx >> 7)) * CC + (idx & 127)];
    if (tid < CC) cpre_s[tid] = cpre[b * CC + tid];
    __syncthreads();

    const int c = tid & 127;
    const int oh = tid >> 7;
    float m[16];
#pragma unroll
    for (int j = 0; j < 16; ++j) m[j] = 0.0f;

    for (int hh = 0; hh < NHEADS; ++hh) {
        for (int idx = tid; idx < HD * CC; idx += 256) {
            int dd = idx >> 7, cc = idx & 127;
            float s = 0.0f;
#pragma unroll
            for (int e = 0; e < HD; ++e)
                s += attn_s[hh * HD + dd][e] * w_qkv[(2 * CC + hh * HD + e) * CC + cc];
            Ph[dd][cc] = s;
        }
        __syncthreads();
#pragma unroll
        for (int dd = 0; dd < HD; ++dd) {
            float p = Ph[dd][c];
#pragma unroll
            for (int j = 0; j < 16; ++j)
                m[j] += wo_s[oh * 16 + j][hh * HD + dd] * p;
        }
        __syncthreads();
    }

    float* mt = Mt + ((size_t)b << 14) + c * CC + og * 32 + oh * 16;
#pragma unroll
    for (int j = 0; j < 16; ++j) mt[j] = m[j];

    if (tid < 32) {
        float s = 0.0f;
        for (int r = 0; r < CC; ++r) s += wo_s[tid][r] * cpre_s[r];
        cvec[b * CC + og * 32 + tid] = s + b_out[og * 32 + tid];
    }
}

// ---------------------------------------------------------------------------
// k3: y = M x + c. grid (64 colchunks, 2 rowhalves, 16 b), 256 threads.
// ---------------------------------------------------------------------------
__global__ __launch_bounds__(256) void k3_out(const float* __restrict__ x,
                                              const float* __restrict__ Mt,
                                              const float* __restrict__ cvec,
                                              float* __restrict__ y) {
    const int chunk = blockIdx.x;
    const int rh = blockIdx.y;
    const int b = blockIdx.z;
    const int tid = threadIdx.x;

    __shared__ float Mts[CC][68];
    __shared__ float cs[64];

    for (int idx = tid; idx < CC * 64; idx += 256) {
        int o = idx & 63, c = idx >> 6;
        Mts[c][o] = Mt[((size_t)b << 14) + c * CC + rh * 64 + o];
    }
    if (tid < 64) cs[tid] = cvec[b * CC + rh * 64 + tid];
    __syncthreads();

    const int rg = tid >> 5;
    const float* xb = x + (size_t)b * CC * NN + chunk * 256 + (tid & 31) * 8;

    float acc[8][8];
#pragma unroll
    for (int u = 0; u < 8; ++u)
#pragma unroll
        for (int w = 0; w < 8; ++w) acc[u][w] = 0.0f;

    for (int c = 0; c < CC; ++c) {
        float4 xa = *(const float4*)&xb[(size_t)c * NN];
        float4 xc4 = *(const float4*)&xb[(size_t)c * NN + 4];
        float4 m0 = *(const float4*)&Mts[c][rg * 8];
        float4 m1 = *(const float4*)&Mts[c][rg * 8 + 4];
        float mr[8] = {m0.x, m0.y, m0.z, m0.w, m1.x, m1.y, m1.z, m1.w};
        float xv[8] = {xa.x, xa.y, xa.z, xa.w, xc4.x, xc4.y, xc4.z, xc4.w};
#pragma unroll
        for (int u = 0; u < 8; ++u)
#pragma unroll
            for (int w = 0; w < 8; ++w) acc[u][w] += mr[u] * xv[w];
    }

    float* yb = y + (size_t)b * CC * NN + (size_t)(rh * 64 + rg * 8) * NN + chunk * 256 + (tid & 31) * 8;
#pragma unroll
    for (int u = 0; u < 8; ++u) {
        float cadd = cs[rg * 8 + u];
        float4 o0 = {acc[u][0] + cadd, acc[u][1] + cadd, acc[u][2] + cadd, acc[u][3] + cadd};
        float4 o1 = {acc[u][4] + cadd, acc[u][5] + cadd, acc[u][6] + cadd, acc[u][7] + cadd};
        *(float4*)&yb[(size_t)u * NN] = o0;
        *(float4*)&yb[(size_t)u * NN + 4] = o1;
    }
}

// ---------------------------------------------------------------------------
extern "C" void kernel_launch(void* const* d_in, const int* in_sizes, int n_in,
                              void* d_out, int out_size, void* d_ws, size_t ws_size,
                              hipStream_t stream) {
    const float* x     = (const float*)d_in[0];
    const float* w_qkv = (const float*)d_in[1];
    const float* b_qkv = (const float*)d_in[2];
    const float* w_out = (const float*)d_in[3];
    const float* b_out = (const float*)d_in[4];
    float* y = (float*)d_out;

    const size_t szG = (size_t)BB * CC * CC;
    const size_t szS = (size_t)BB * CC;
    const size_t szAttn = (size_t)BB * NHEADS * HD * HD;
    const size_t tail = szG + szS + szAttn + szS + szG + szS;

    int CH = 32;
    while (CH > 1 &&
           ((size_t)CH * BB * 10240 + (size_t)CH * BB * CC + tail) * sizeof(float) > ws_size)
        CH >>= 1;

    float* pG   = (float*)d_ws;
    float* pS   = pG + (size_t)CH * BB * 10240;   // 10 upper tiles * 1024 per (b,chunk)
    float* G    = pS + (size_t)CH * BB * CC;
    float* sB   = G + szG;
    float* attn = sB + szS;
    float* cpre = attn + szAttn;
    float* Mt   = cpre + szS;
    float* cvec = Mt + szG;

    k1_gram<<<dim3(CH, BB), 256, 0, stream>>>(x, pG, pS, CH);
    k1_reduce<<<dim3(41, BB), 256, 0, stream>>>(pG, pS, G, sB, CH);
    k2a_attn<<<dim3(NHEADS, BB), 256, 0, stream>>>(G, sB, w_qkv, b_qkv, attn, cpre);
    k2b_M<<<dim3(4, BB), 256, 0, stream>>>(attn, cpre, w_qkv, w_out, b_out, Mt, cvec);
    k3_out<<<dim3(64, 2, BB), 256, 0, stream>>>(x, Mt, cvec, y);
}

// Round 2
// 347.460 us; speedup vs baseline: 1.3865x; 1.2055x over previous
//
#include <hip/hip_runtime.h>
#include <math.h>

// Problem constants
#define BB 16
#define CC 128
#define NN 16384          // 128*128 spatial tokens
#define NHEADS 8
#define HD 16             // head dim
#define SCALE 0.08838834764831843f   // 1/sqrt(128)

typedef __attribute__((ext_vector_type(8))) short short8;
typedef __attribute__((ext_vector_type(4))) unsigned short ushort4v;
typedef __attribute__((ext_vector_type(16))) float f32x16;

// Truncation bf16 split: hi = trunc16(v), lo = trunc16(v - hi)  (v-hi exact in fp32)
#define CVT(comp, hh, ll)                                                    \
    {                                                                        \
        unsigned int u = __float_as_uint(comp);                              \
        hh = (unsigned short)(u >> 16);                                      \
        float lf = (comp) - __uint_as_float(u & 0xffff0000u);                \
        ll = (unsigned short)(__float_as_uint(lf) >> 16);                    \
    }

// ---------------------------------------------------------------------------
// k1: per-batch partial Gram via split-bf16 MFMA (3-term: hh+hl+lh).
// grid (CH, 16 b), 256 threads (4 waves). LDS [ch][64 tok] bf16, XOR-swizzled
// (ushort idx ^= (ch&7)<<3) so column-strided ds_read_b128 is conflict-free.
// ---------------------------------------------------------------------------
__global__ __launch_bounds__(256) void k1_gram(const float* __restrict__ x,
                                               float* __restrict__ pG,
                                               float* __restrict__ pS,
                                               int CH) {
    const int chunk = blockIdx.x;
    const int b = blockIdx.y;
    const int tid = threadIdx.x;
    const int w = tid >> 6;          // wave 0..3
    const int l = tid & 63;
    const int ch0 = tid >> 4;        // staging: channel base 0..15
    const int t4 = tid & 15;         // staging: float4 index within 64-token stage
    const int NCB = NN / CH;
    const int NSTAGE = NCB >> 6;

    __shared__ __align__(16) unsigned short lds[2][2][128 * 64];  // [buf][hi/lo][ch*64+tok]

    const float* xg = x + (size_t)b * CC * NN + (size_t)chunk * NCB;

    f32x16 acc[10];
#pragma unroll
    for (int t = 0; t < 10; ++t)
#pragma unroll
        for (int r = 0; r < 16; ++r) acc[t][r] = 0.0f;

    float csum[8];
#pragma unroll
    for (int k = 0; k < 8; ++k) csum[k] = 0.0f;

    float4 ld[8];

    auto LOAD = [&](int s) {
#pragma unroll
        for (int k = 0; k < 8; ++k)
            ld[k] = *(const float4*)(xg + (size_t)(ch0 + 16 * k) * NN + s * 64 + t4 * 4);
    };

    auto CVW = [&](int buf) {
#pragma unroll
        for (int k = 0; k < 8; ++k) {
            float4 v = ld[k];
            csum[k] += v.x + v.y + v.z + v.w;
            const int ch = ch0 + 16 * k;
            const int idx = ((ch << 6) + (t4 << 2)) ^ ((ch & 7) << 3);
            unsigned short h0, h1, h2, h3, l0, l1, l2, l3;
            CVT(v.x, h0, l0)
            CVT(v.y, h1, l1)
            CVT(v.z, h2, l2)
            CVT(v.w, h3, l3)
            ushort4v hv = {h0, h1, h2, h3};
            ushort4v lv = {l0, l1, l2, l3};
            *(ushort4v*)&lds[buf][0][idx] = hv;
            *(ushort4v*)&lds[buf][1][idx] = lv;
        }
    };

    const int lr = l & 31, lh = l >> 5;

    LOAD(0);
    CVW(0);
    __syncthreads();

    for (int s = 0; s < NSTAGE; ++s) {
        const int bsel = s & 1;
        if (s + 1 < NSTAGE) LOAD(s + 1);     // prefetch under compute

        short8 fh[4], fl[4];
        const int tb = w * 16 + lh * 8;      // token offset of this wave's K-slice
#pragma unroll
        for (int cb = 0; cb < 4; ++cb) {
            const int ch = cb * 32 + lr;
            const int idx = ((ch << 6) + tb) ^ ((ch & 7) << 3);
            fh[cb] = *(const short8*)&lds[bsel][0][idx];
            fl[cb] = *(const short8*)&lds[bsel][1][idx];
        }

#define TILE(t, bi, bj)                                                                      \
        acc[t] = __builtin_amdgcn_mfma_f32_32x32x16_bf16(fh[bi], fh[bj], acc[t], 0, 0, 0);   \
        acc[t] = __builtin_amdgcn_mfma_f32_32x32x16_bf16(fh[bi], fl[bj], acc[t], 0, 0, 0);   \
        acc[t] = __builtin_amdgcn_mfma_f32_32x32x16_bf16(fl[bi], fh[bj], acc[t], 0, 0, 0);
        TILE(0, 0, 0) TILE(1, 0, 1) TILE(2, 0, 2) TILE(3, 0, 3) TILE(4, 1, 1)
        TILE(5, 1, 2) TILE(6, 1, 3) TILE(7, 2, 2) TILE(8, 2, 3) TILE(9, 3, 3)
#undef TILE

        if (s + 1 < NSTAGE) CVW((s + 1) & 1);
        __syncthreads();
    }

    // ---- channel sums -> pS (reuse LDS as float scratch) ----
    float* scr = (float*)&lds[0][0][0];
#pragma unroll
    for (int k = 0; k < 8; ++k) scr[(ch0 + 16 * k) * 16 + t4] = csum[k];
    __syncthreads();
    if (tid < 128) {
        float s2 = 0.0f;
#pragma unroll
        for (int i = 0; i < 16; ++i) s2 += scr[tid * 16 + i];
        pS[(size_t)(b * CH + chunk) * 128 + tid] = s2;
    }
    __syncthreads();

    // ---- cross-wave reduce of the 10 tiles, store partial Gram ----
    float* outp = pG + (size_t)(b * CH + chunk) * 10240;
#pragma unroll
    for (int half = 0; half < 2; ++half) {
        if (w > 0) {
#pragma unroll
            for (int tt = 0; tt < 5; ++tt)
#pragma unroll
                for (int r = 0; r < 16; ++r)
                    scr[((w - 1) * 5 + tt) * 1024 + r * 64 + l] = acc[half * 5 + tt][r];
        }
        __syncthreads();
        if (w == 0) {
#pragma unroll
            for (int tt = 0; tt < 5; ++tt)
#pragma unroll
                for (int r = 0; r < 16; ++r)
                    outp[(half * 5 + tt) * 1024 + r * 64 + l] =
                        acc[half * 5 + tt][r]
                        + scr[(0 * 5 + tt) * 1024 + r * 64 + l]
                        + scr[(1 * 5 + tt) * 1024 + r * 64 + l]
                        + scr[(2 * 5 + tt) * 1024 + r * 64 + l];
        }
        __syncthreads();
    }
}

// ---------------------------------------------------------------------------
// k1r: reduce partial Grams -> G (with symmetric mirror), pS -> sB.
// MFMA C/D layout: col = lane&31, row = (reg&3) + 8*(reg>>2) + 4*(lane>>5).
// ---------------------------------------------------------------------------
__global__ __launch_bounds__(256) void k1_reduce(const float* __restrict__ pG,
                                                 const float* __restrict__ pS,
                                                 float* __restrict__ G,
                                                 float* __restrict__ sB,
                                                 int CH) {
    const int sg = blockIdx.x;
    const int b = blockIdx.y;
    const int tid = threadIdx.x;

    if (sg < 40) {
        const int e = sg * 256 + tid;       // 0..10239
        const int t = e >> 10;              // tile id (uniform per block)
        const int rl = e & 1023;
        float sum = 0.0f;
        const float* p = pG + (size_t)b * CH * 10240 + e;
        for (int ch = 0; ch < CH; ++ch) sum += p[(size_t)ch * 10240];

        int bi, bj;
        if (t < 4)      { bi = 0; bj = t; }
        else if (t < 7) { bi = 1; bj = t - 3; }
        else if (t < 9) { bi = 2; bj = t - 5; }
        else            { bi = 3; bj = 3; }

        const int reg = rl >> 6, lane = rl & 63;
        const int col = bj * 32 + (lane & 31);
        const int row = bi * 32 + (reg & 3) + 8 * (reg >> 2) + 4 * (lane >> 5);
        G[((size_t)b << 14) + row * CC + col] = sum;
        if (bi != bj) G[((size_t)b << 14) + col * CC + row] = sum;
    } else {
        if (tid < 128) {
            float s2 = 0.0f;
            for (int ch = 0; ch < CH; ++ch) s2 += pS[(size_t)(b * CH + ch) * 128 + tid];
            sB[b * CC + tid] = s2;
        }
    }
}

// ---------------------------------------------------------------------------
// k2a: per (b,h) scores + softmax. grid (8 h, 16 b), 256 threads.
// scores = (Wq G Wk^T + (Wq s) bk^T + bq (Wk s)^T + N bq bk^T) * SCALE
// ---------------------------------------------------------------------------
__global__ __launch_bounds__(256) void k2a_attn(const float* __restrict__ G,
                                                const float* __restrict__ sB,
                                                const float* __restrict__ w_qkv,
                                                const float* __restrict__ b_qkv,
                                                float* __restrict__ attn,
                                                float* __restrict__ cpre) {
    const int h = blockIdx.x;
    const int b = blockIdx.y;
    const int tid = threadIdx.x;

    __shared__ float wq_s[HD][132], wk_s[HD][132], Tq[HD][132];
    __shared__ float qs[HD], ks[HD], bqv[HD], bkv[HD], bvv[HD];
    __shared__ float sc[HD][HD + 1];

    for (int idx = tid; idx < HD * CC; idx += 256) {
        int r = idx >> 7, c = idx & 127;
        wq_s[r][c] = w_qkv[(h * HD + r) * CC + c];
        wk_s[r][c] = w_qkv[(CC + h * HD + r) * CC + c];
    }
    if (tid < HD) {
        bqv[tid] = b_qkv[h * HD + tid];
        bkv[tid] = b_qkv[CC + h * HD + tid];
        bvv[tid] = b_qkv[2 * CC + h * HD + tid];
    }
    __syncthreads();

    if (tid < 32) {
        int i = tid & 15;
        bool isK = tid >= 16;
        float sum = 0.0f;
        for (int c = 0; c < CC; ++c)
            sum += (isK ? wk_s[i][c] : wq_s[i][c]) * sB[b * CC + c];
        if (isK) ks[i] = sum; else qs[i] = sum;
    }

    {
        const int c2 = tid & 127;
        const int dh = tid >> 7;
        float t[8];
#pragma unroll
        for (int j = 0; j < 8; ++j) t[j] = 0.0f;
        const float* Gb = G + ((size_t)b << 14);
        for (int c1 = 0; c1 < CC; ++c1) {
            float g = Gb[c1 * CC + c2];
#pragma unroll
            for (int j = 0; j < 8; ++j) t[j] += wq_s[dh * 8 + j][c1] * g;
        }
        __syncthreads();
#pragma unroll
        for (int j = 0; j < 8; ++j) Tq[dh * 8 + j][c2] = t[j];
    }
    __syncthreads();

    {
        const int dd = tid >> 4, e = tid & 15;
        float sum = 0.0f;
        for (int c2 = 0; c2 < CC; ++c2) sum += Tq[dd][c2] * wk_s[e][c2];
        sum += qs[dd] * bkv[e] + bqv[dd] * ks[e] + (float)NN * bqv[dd] * bkv[e];
        sc[dd][e] = sum * SCALE;
    }
    __syncthreads();

    if (tid < HD) {
        const int dd = tid;
        float mx = -1e30f;
#pragma unroll
        for (int e = 0; e < HD; ++e) mx = fmaxf(mx, sc[dd][e]);
        float ex[HD];
        float den = 0.0f;
#pragma unroll
        for (int e = 0; e < HD; ++e) { ex[e] = __expf(sc[dd][e] - mx); den += ex[e]; }
        float inv = 1.0f / den;
        float cp = 0.0f;
#pragma unroll
        for (int e = 0; e < HD; ++e) {
            float a = ex[e] * inv;
            attn[((size_t)b * NHEADS + h) * HD * HD + dd * HD + e] = a;
            cp += a * bvv[e];
        }
        cpre[b * CC + h * HD + dd] = cp;
    }
}

// ---------------------------------------------------------------------------
// k2b: M = W_out * blockdiag(attn) * W_v, emitted as bf16 hi/lo planes
// Mh/Ml[b][o][c] (row-major, A-fragment-friendly). cvec = W_out cpre + b_out.
// grid (4 ogroups, 16 b), 256 threads.
// ---------------------------------------------------------------------------
__global__ __launch_bounds__(256) void k2b_M(const float* __restrict__ attn,
                                             const float* __restrict__ cpre,
                                             const float* __restrict__ w_qkv,
                                             const float* __restrict__ w_out,
                                             const float* __restrict__ b_out,
                                             unsigned short* __restrict__ Mh,
                                             unsigned short* __restrict__ Ml,
                                             float* __restrict__ cvec) {
    const int og = blockIdx.x;
    const int b = blockIdx.y;
    const int tid = threadIdx.x;

    __shared__ float Ph[HD][132];
    __shared__ float wo_s[32][129];
    __shared__ float attn_s[CC][HD];
    __shared__ float cpre_s[CC];

    for (int idx = tid; idx < CC * HD; idx += 256)
        attn_s[idx >> 4][idx & 15] = attn[(size_t)b * CC * HD + idx];
    for (int idx = tid; idx < 32 * CC; idx += 256)
        wo_s[idx >> 7][idx & 127] = w_out[(og * 32 + (idx >> 7)) * CC + (idx & 127)];
    if (tid < CC) cpre_s[tid] = cpre[b * CC + tid];
    __syncthreads();

    const int c = tid & 127;
    const int oh = tid >> 7;
    float m[16];
#pragma unroll
    for (int j = 0; j < 16; ++j) m[j] = 0.0f;

    for (int hh = 0; hh < NHEADS; ++hh) {
        for (int idx = tid; idx < HD * CC; idx += 256) {
            int dd = idx >> 7, cc = idx & 127;
            float s = 0.0f;
#pragma unroll
            for (int e = 0; e < HD; ++e)
                s += attn_s[hh * HD + dd][e] * w_qkv[(2 * CC + hh * HD + e) * CC + cc];
            Ph[dd][cc] = s;
        }
        __syncthreads();
#pragma unroll
        for (int dd = 0; dd < HD; ++dd) {
            float p = Ph[dd][c];
#pragma unroll
            for (int j = 0; j < 16; ++j)
                m[j] += wo_s[oh * 16 + j][hh * HD + dd] * p;
        }
        __syncthreads();
    }

#pragma unroll
    for (int j = 0; j < 16; ++j) {
        const int o = og * 32 + oh * 16 + j;
        unsigned short hh2, ll2;
        CVT(m[j], hh2, ll2)
        Mh[((size_t)b << 14) + o * CC + c] = hh2;
        Ml[((size_t)b << 14) + o * CC + c] = ll2;
    }

    if (tid < 32) {
        float s = 0.0f;
        for (int r = 0; r < CC; ++r) s += wo_s[tid][r] * cpre_s[r];
        cvec[b * CC + og * 32 + tid] = s + b_out[og * 32 + tid];
    }
}

// ---------------------------------------------------------------------------
// k3: y = M x + c via split-bf16 MFMA (3-term). grid (128 chunks, 16 b),
// 256 threads = 4 waves. Block: all 128 o x 128 tokens; wave w owns o-slice
// [32w, 32w+32). Two 64-token stages, double-buffered LDS x^T planes
// [n][c] (ushort idx c ^= (n&7)<<3 swizzle). M hi/lo fragments preloaded
// to registers from k2b's planes.
// ---------------------------------------------------------------------------
__global__ __launch_bounds__(256) void k3_out(const float* __restrict__ x,
                                              const unsigned short* __restrict__ Mh,
                                              const unsigned short* __restrict__ Ml,
                                              const float* __restrict__ cvec,
                                              float* __restrict__ y) {
    const int chunk = blockIdx.x;
    const int b = blockIdx.y;
    const int tid = threadIdx.x;
    const int w = tid >> 6;
    const int lane = tid & 63;

    __shared__ __align__(16) unsigned short xs[2][2][64 * 128];  // [buf][hi/lo][n*128+c]

    const float* xb = x + (size_t)b * CC * NN + (size_t)chunk * 128;

    // ---- preload M fragments for this wave's 32 output rows ----
    short8 Ah[8], Al[8];
    {
        const size_t mbase = ((size_t)b << 14) + (size_t)(32 * w + (lane & 31)) * CC;
#pragma unroll
        for (int ks = 0; ks < 8; ++ks) {
            const size_t off = mbase + 16 * ks + 8 * (lane >> 5);
            Ah[ks] = *(const short8*)&Mh[off];
            Al[ks] = *(const short8*)&Ml[off];
        }
    }

    f32x16 acc[4];
#pragma unroll
    for (int t = 0; t < 4; ++t)
#pragma unroll
        for (int r = 0; r < 16; ++r) acc[t][r] = 0.0f;

    float ldv[8][4];

    auto LOAD = [&](int s) {
#pragma unroll
        for (int k = 0; k < 8; ++k) {
            const int c0 = w * 4 + k * 16;
#pragma unroll
            for (int i = 0; i < 4; ++i)
                ldv[k][i] = xb[(size_t)(c0 + i) * NN + s * 64 + lane];
        }
    };

    auto CVW = [&](int buf) {
#pragma unroll
        for (int k = 0; k < 8; ++k) {
            const int c0 = w * 4 + k * 16;
            const int idx = lane * 128 + (c0 ^ ((lane & 7) << 3));
            ushort4v hv, lv;
#pragma unroll
            for (int i = 0; i < 4; ++i) {
                unsigned short hh, ll;
                CVT(ldv[k][i], hh, ll)
                hv[i] = hh;
                lv[i] = ll;
            }
            *(ushort4v*)&xs[buf][0][idx] = hv;
            *(ushort4v*)&xs[buf][1][idx] = lv;
        }
    };

    LOAD(0);
    CVW(0);
    __syncthreads();

#pragma unroll
    for (int s = 0; s < 2; ++s) {
        if (s == 0) LOAD(1);
#pragma unroll
        for (int nt = 0; nt < 2; ++nt) {
            const int nl = nt * 32 + (lane & 31);
            const int cxor = (nl & 7) << 3;
            const int rowb = nl * 128;
#pragma unroll
            for (int ks = 0; ks < 8; ++ks) {
                const int idx = rowb + ((16 * ks + 8 * (lane >> 5)) ^ cxor);
                short8 bh = *(const short8*)&xs[s][0][idx];
                short8 bl = *(const short8*)&xs[s][1][idx];
                const int t = s * 2 + nt;
                acc[t] = __builtin_amdgcn_mfma_f32_32x32x16_bf16(Ah[ks], bh, acc[t], 0, 0, 0);
                acc[t] = __builtin_amdgcn_mfma_f32_32x32x16_bf16(Ah[ks], bl, acc[t], 0, 0, 0);
                acc[t] = __builtin_amdgcn_mfma_f32_32x32x16_bf16(Al[ks], bh, acc[t], 0, 0, 0);
            }
        }
        if (s == 0) CVW(1);
        __syncthreads();
    }

    // ---- epilogue: y[o][n] = acc + cvec[o] ----
    float cvv[16];
#pragma unroll
    for (int r = 0; r < 16; ++r)
        cvv[r] = cvec[b * CC + 32 * w + (r & 3) + 8 * (r >> 2) + 4 * (lane >> 5)];

    float* yb = y + (size_t)b * CC * NN + (size_t)chunk * 128;
#pragma unroll
    for (int t = 0; t < 4; ++t) {
        const int n = t * 32 + (lane & 31);
#pragma unroll
        for (int r = 0; r < 16; ++r) {
            const int o = 32 * w + (r & 3) + 8 * (r >> 2) + 4 * (lane >> 5);
            yb[(size_t)o * NN + n] = acc[t][r] + cvv[r];
        }
    }
}

// ---------------------------------------------------------------------------
extern "C" void kernel_launch(void* const* d_in, const int* in_sizes, int n_in,
                              void* d_out, int out_size, void* d_ws, size_t ws_size,
                              hipStream_t stream) {
    const float* x     = (const float*)d_in[0];
    const float* w_qkv = (const float*)d_in[1];
    const float* b_qkv = (const float*)d_in[2];
    const float* w_out = (const float*)d_in[3];
    const float* b_out = (const float*)d_in[4];
    float* y = (float*)d_out;

    const size_t szG = (size_t)BB * CC * CC;
    const size_t szS = (size_t)BB * CC;
    const size_t szAttn = (size_t)BB * NHEADS * HD * HD;
    const size_t tail = szG + szS + szAttn + szS + szG + szS;

    int CH = 32;
    while (CH > 1 &&
           ((size_t)CH * BB * 10240 + (size_t)CH * BB * CC + tail) * sizeof(float) > ws_size)
        CH >>= 1;

    float* pG   = (float*)d_ws;
    float* pS   = pG + (size_t)CH * BB * 10240;   // 10 upper tiles * 1024 per (b,chunk)
    float* G    = pS + (size_t)CH * BB * CC;
    float* sB   = G + szG;
    float* attn = sB + szS;
    float* cpre = attn + szAttn;
    float* Mslab = cpre + szS;                    // szG floats = Mh + Ml ushort planes
    float* cvec = Mslab + szG;

    unsigned short* Mh = (unsigned short*)Mslab;
    unsigned short* Ml = Mh + (size_t)BB * CC * CC;

    k1_gram<<<dim3(CH, BB), 256, 0, stream>>>(x, pG, pS, CH);
    k1_reduce<<<dim3(41, BB), 256, 0, stream>>>(pG, pS, G, sB, CH);
    k2a_attn<<<dim3(NHEADS, BB), 256, 0, stream>>>(G, sB, w_qkv, b_qkv, attn, cpre);
    k2b_M<<<dim3(4, BB), 256, 0, stream>>>(attn, cpre, w_qkv, w_out, b_out, Mh, Ml, cvec);
    k3_out<<<dim3(128, BB), 256, 0, stream>>>(x, Mh, Ml, cvec, y);
}